// Round 1
// 108.659 us; speedup vs baseline: 1.0566x; 1.0566x over previous
//
#include <hip/hip_runtime.h>
#include <math.h>

#define N_V 12288
#define D_F 32
#define N_E 196608
#define KNN 6
#define EPSF 1e-12f

#define SEGS 8
#define JSEG (N_V / SEGS)          // 1536 candidate columns per segment
#define SUBTILES (JSEG / 16)       // 96 j-subtiles per segment
#define ROWS_PER_BLOCK 128         // 4 waves x 32 query rows
#define ROW_BLOCKS (N_V / ROWS_PER_BLOCK)  // 96 -> grid 96 x 8 = 768 blocks (3/CU, fully resident)
#define NKEEP 5                    // top-5 non-self keys kept per (row, seg)

typedef __bf16 bf16x8 __attribute__((ext_vector_type(8)));
typedef float f32x4 __attribute__((ext_vector_type(4)));

static_assert(N_V % ROWS_PER_BLOCK == 0, "");
static_assert(SUBTILES % 4 == 0, "");
static_assert(JSEG % ROWS_PER_BLOCK == 0, "");

__device__ __forceinline__ unsigned short f2bf(float f) {
    unsigned u = __builtin_bit_cast(unsigned, f);
    unsigned r = u + 0x7fffu + ((u >> 16) & 1u);   // RNE
    return (unsigned short)(r >> 16);
}

// descending sorted 5-list insert: 1 max + 4 med3
__device__ __forceinline__ void ins5(float s[NKEEP], float nv) {
    float y0 = fmaxf(s[0], nv);
    float y1 = __builtin_amdgcn_fmed3f(s[0], s[1], nv);
    float y2 = __builtin_amdgcn_fmed3f(s[1], s[2], nv);
    float y3 = __builtin_amdgcn_fmed3f(s[2], s[3], nv);
    float y4 = __builtin_amdgcn_fmed3f(s[3], s[4], nv);
    s[0] = y0; s[1] = y1; s[2] = y2; s[3] = y3; s[4] = y4;
}

// descending sorted 6-list insert: 1 max + 5 med3 (diagonal blocks: self + top-5)
__device__ __forceinline__ void ins6(float s[KNN], float nv) {
    float y0 = fmaxf(s[0], nv);
    float y1 = __builtin_amdgcn_fmed3f(s[0], s[1], nv);
    float y2 = __builtin_amdgcn_fmed3f(s[1], s[2], nv);
    float y3 = __builtin_amdgcn_fmed3f(s[2], s[3], nv);
    float y4 = __builtin_amdgcn_fmed3f(s[3], s[4], nv);
    float y5 = __builtin_amdgcn_fmed3f(s[4], s[5], nv);
    s[0] = y0; s[1] = y1; s[2] = y2; s[3] = y3; s[4] = y4; s[5] = y5;
}

// ---------- kernel 0: bf16 convert + msq(-0.5*sq), 8 threads/row ----------
__global__ __launch_bounds__(256) void prep_kernel(const float* __restrict__ x,
                                                   unsigned short* __restrict__ xb,
                                                   float* __restrict__ msq) {
    const int gid = blockIdx.x * 256 + threadIdx.x;   // 0..98303
    const int row = gid >> 3;
    const int h = gid & 7;
    float4 p = ((const float4*)(x + (size_t)row * D_F))[h];
    float s = p.x * p.x + p.y * p.y + p.z * p.z + p.w * p.w;
    s += __shfl_xor(s, 1, 64);
    s += __shfl_xor(s, 2, 64);
    s += __shfl_xor(s, 4, 64);
    const unsigned lo = (unsigned)f2bf(p.x) | ((unsigned)f2bf(p.y) << 16);
    const unsigned hi = (unsigned)f2bf(p.z) | ((unsigned)f2bf(p.w) << 16);
    ((uint2*)xb)[gid] = make_uint2(lo, hi);
    if (h == 0) msq[row] = -0.5f * s;
}

// ---------- kernel 1: MFMA gram + per-row top-5 (non-self) keys ----------
// A = candidate rows (j), B = query rows (i). C[m=quad*4+reg][n=l16]:
// lane's query row = rowbase + rt*16 + l16, candidates j = col0 + quad*4 + reg.
// acc init = msq[j] => C = dot - 0.5*sq_j (selection key; larger == closer).
// Batched 4-subtile structure: 8 loads -> 8 MFMAs -> 32 inserts, all results
// live in registers simultaneously (needs ~100 VGPR -> launch_bounds(256,4)).
__global__ __launch_bounds__(256, 4) void topk_mfma(
    const unsigned short* __restrict__ xb, const float* __restrict__ msq,
    float* __restrict__ cand) {
    const int t = threadIdx.x;
    const int wave = t >> 6;
    const int lane = t & 63;
    const int quad = lane >> 4;
    const int l16 = lane & 15;

    const int rowbase = blockIdx.x * ROWS_PER_BLOCK + wave * 32;
    const int seg = blockIdx.y;
    const int j0 = seg * JSEG;

    // B fragments: query rows, register-resident
    bf16x8 bfrag[2];
#pragma unroll
    for (int rt = 0; rt < 2; ++rt)
        bfrag[rt] = *reinterpret_cast<const bf16x8*>(
            xb + (size_t)(rowbase + rt * 16 + l16) * D_F + quad * 8);

    const unsigned short* aptr = xb + (size_t)(j0 + l16) * D_F + quad * 8;
    const float* mptr = msq + j0 + quad * 4;

    // does this block's row range intersect this segment's columns? (self key present)
    const bool diag = ((unsigned)(rowbase - j0) < (unsigned)JSEG);

    if (!diag) {
        // ---- clean path: top-5 lists, no self column in range ----
        float tk[2][NKEEP];
#pragma unroll
        for (int rt = 0; rt < 2; ++rt)
#pragma unroll
            for (int k = 0; k < NKEEP; ++k) tk[rt][k] = -3.0e38f;

        for (int it = 0; it < SUBTILES; it += 4) {
            bf16x8 a[4];
            f32x4 mm[4];
#pragma unroll
            for (int u = 0; u < 4; ++u) {
                a[u] = *reinterpret_cast<const bf16x8*>(aptr + u * (16 * D_F));
                mm[u] = *reinterpret_cast<const f32x4*>(mptr + u * 16);
            }
            f32x4 c[4][2];
#pragma unroll
            for (int u = 0; u < 4; ++u) {
                c[u][0] = __builtin_amdgcn_mfma_f32_16x16x32_bf16(a[u], bfrag[0], mm[u], 0, 0, 0);
                c[u][1] = __builtin_amdgcn_mfma_f32_16x16x32_bf16(a[u], bfrag[1], mm[u], 0, 0, 0);
            }
#pragma unroll
            for (int u = 0; u < 4; ++u)
#pragma unroll
                for (int rt = 0; rt < 2; ++rt) {
                    ins5(tk[rt], c[u][rt][0]);
                    ins5(tk[rt], c[u][rt][1]);
                    ins5(tk[rt], c[u][rt][2]);
                    ins5(tk[rt], c[u][rt][3]);
                }
            aptr += 4 * 16 * D_F;
            mptr += 4 * 16;
        }

        // cross-quad merge via shuffles (row's lists live in 4 quads, same l16)
#pragma unroll
        for (int rt = 0; rt < 2; ++rt) {
#pragma unroll
            for (int rnd = 0; rnd < 2; ++rnd) {
                const int mask = 16 << rnd;
                float b[NKEEP];
#pragma unroll
                for (int k = 0; k < NKEEP; ++k) b[k] = __shfl_xor(tk[rt][k], mask, 64);
#pragma unroll
                for (int k = 0; k < NKEEP; ++k) ins5(tk[rt], b[k]);
            }
        }

        if (quad == 0) {
#pragma unroll
            for (int rt = 0; rt < 2; ++rt) {
                const int g = rowbase + rt * 16 + l16;
                float* dst = cand + ((size_t)g * SEGS + seg) * NKEEP;
#pragma unroll
                for (int k = 0; k < NKEEP; ++k) dst[k] = tk[rt][k];
            }
        }
    } else {
        // ---- diagonal path: top-6 lists; slot 0 == self (segment max), dropped on write ----
        float tk[2][KNN];
#pragma unroll
        for (int rt = 0; rt < 2; ++rt)
#pragma unroll
            for (int k = 0; k < KNN; ++k) tk[rt][k] = -3.0e38f;

        for (int it = 0; it < SUBTILES; it += 4) {
            bf16x8 a[4];
            f32x4 mm[4];
#pragma unroll
            for (int u = 0; u < 4; ++u) {
                a[u] = *reinterpret_cast<const bf16x8*>(aptr + u * (16 * D_F));
                mm[u] = *reinterpret_cast<const f32x4*>(mptr + u * 16);
            }
            f32x4 c[4][2];
#pragma unroll
            for (int u = 0; u < 4; ++u) {
                c[u][0] = __builtin_amdgcn_mfma_f32_16x16x32_bf16(a[u], bfrag[0], mm[u], 0, 0, 0);
                c[u][1] = __builtin_amdgcn_mfma_f32_16x16x32_bf16(a[u], bfrag[1], mm[u], 0, 0, 0);
            }
#pragma unroll
            for (int u = 0; u < 4; ++u)
#pragma unroll
                for (int rt = 0; rt < 2; ++rt) {
                    ins6(tk[rt], c[u][rt][0]);
                    ins6(tk[rt], c[u][rt][1]);
                    ins6(tk[rt], c[u][rt][2]);
                    ins6(tk[rt], c[u][rt][3]);
                }
            aptr += 4 * 16 * D_F;
            mptr += 4 * 16;
        }

#pragma unroll
        for (int rt = 0; rt < 2; ++rt) {
#pragma unroll
            for (int rnd = 0; rnd < 2; ++rnd) {
                const int mask = 16 << rnd;
                float b[KNN];
#pragma unroll
                for (int k = 0; k < KNN; ++k) b[k] = __shfl_xor(tk[rt][k], mask, 64);
#pragma unroll
                for (int k = 0; k < KNN; ++k) ins6(tk[rt], b[k]);
            }
        }

        if (quad == 0) {
#pragma unroll
            for (int rt = 0; rt < 2; ++rt) {
                const int g = rowbase + rt * 16 + l16;
                float* dst = cand + ((size_t)g * SEGS + seg) * NKEEP;
#pragma unroll
                for (int k = 1; k < KNN; ++k) dst[k - 1] = tk[rt][k];  // drop self (slot 0)
            }
        }
    }
}

// ---------- kernel 2: merge per-segment keys -> v, 2 threads/row ----------
__global__ __launch_bounds__(256) void merge_v(const float* __restrict__ cand,
                                               const float* __restrict__ msq,
                                               float* __restrict__ v,
                                               float* __restrict__ out) {
    const int gid = blockIdx.x * 256 + threadIdx.x;   // 0..24575
    const int row = gid >> 1;
    const int h = gid & 1;
    const float4* c = (const float4*)(cand + (size_t)row * (SEGS * NKEEP));  // 10 x float4
    float mk[NKEEP];
#pragma unroll
    for (int k = 0; k < NKEEP; ++k) mk[k] = -3.0e38f;
#pragma unroll
    for (int s = 0; s < 5; ++s) {
        float4 q = c[h + 2 * s];
        ins5(mk, q.x); ins5(mk, q.y); ins5(mk, q.z); ins5(mk, q.w);
    }
    // merge across the lane pair of this row
    {
        float b[NKEEP];
#pragma unroll
        for (int k = 0; k < NKEEP; ++k) b[k] = __shfl_xor(mk[k], 1, 64);
#pragma unroll
        for (int k = 0; k < NKEEP; ++k) ins5(mk, b[k]);
    }
    if (h == 0) {
        const float msqi = msq[row];
        float ssum = 0.f;
#pragma unroll
        for (int m = 0; m < NKEEP; ++m) {
            const float d2 = -2.0f * (mk[m] + msqi);   // sq_i - 2*key
            ssum += expf(-sqrtf(fmaxf(d2, EPSF)));
        }
        const float vi = 1.0f - ssum / (float)KNN;
        v[row] = vi;
        out[2 * row] = vi;
        out[2 * row + 1] = 0.0f;
    }
}

// ---------- kernel 3: edge filtration ----------
__global__ __launch_bounds__(256) void edge_kernel(const float* __restrict__ x,
                                                   const int* __restrict__ ei,
                                                   const float* __restrict__ v,
                                                   float* __restrict__ out) {
    int e = blockIdx.x * 256 + threadIdx.x;
    if (e >= N_E) return;
    const int u = ei[e];
    const int w = ei[N_E + e];
    const float4* xu = (const float4*)(x + (size_t)u * D_F);
    const float4* xw = (const float4*)(x + (size_t)w * D_F);
    float a0 = 0.f, a1 = 0.f, a2 = 0.f, a3 = 0.f;
#pragma unroll
    for (int d = 0; d < 8; ++d) {
        float4 p = xu[d], q = xw[d];
        float dx = p.x - q.x, dy = p.y - q.y, dz = p.z - q.z, dw = p.w - q.w;
        a0 += dx * dx; a1 += dy * dy; a2 += dz * dz; a3 += dw * dw;
    }
    const float enorm = sqrtf(fmaxf((a0 + a1) + (a2 + a3), EPSF));
    const float ey = 1.0f - expf(-enorm);
    const float ev = fmaxf(v[u], v[w]);
    out[2 * (N_V + e) + 0] = ev;
    out[2 * (N_V + e) + 1] = ey;
}

extern "C" void kernel_launch(void* const* d_in, const int* in_sizes, int n_in,
                              void* d_out, int out_size, void* d_ws, size_t ws_size,
                              hipStream_t stream) {
    const float* x = (const float*)d_in[0];
    const int* ei = (const int*)d_in[1];
    float* out = (float*)d_out;
    char* ws = (char*)d_ws;

    unsigned short* xb = (unsigned short*)ws;                  // 786432 B
    float* msq = (float*)(ws + 786432);                        // 49152 B
    float* v   = (float*)(ws + 786432 + 49152);                // 49152 B
    float* cand = (float*)(ws + 786432 + 2 * 49152);           // 12288*8*5*4 = 1966080 B

    prep_kernel<<<(N_V * 8) / 256, 256, 0, stream>>>(x, xb, msq);

    dim3 g1(ROW_BLOCKS, SEGS);
    topk_mfma<<<g1, 256, 0, stream>>>(xb, msq, cand);

    merge_v<<<(N_V * 2) / 256, 256, 0, stream>>>(cand, msq, v, out);

    edge_kernel<<<N_E / 256, 256, 0, stream>>>(x, ei, v, out);
}